// Round 3
// baseline (303.544 us; speedup 1.0000x reference)
//
#include <hip/hip_runtime.h>
#include <math.h>

// Model: review-based recommender. ALL float tensors fp32.
// Shapes: VOCAB=20000, D=100, H=100, K=3, N_U=N_I=256, R=8, S=52, Sp=50, E=20000.
// Outputs (fp32, flat): pred_r[20000] @0, pred_c[20000] @20000,
//                       z_u[102400] @40000, z_i[102400] @142400.

__device__ __forceinline__ float sigmoidf_(float x) { return 1.f / (1.f + expf(-x)); }

// ---------------------------------------------------------------------------
// K0: prep. Wt[kk=300][h=100] = conv_w[h][kk]; fc2t[h=100][dd=100] = fc_w2_w[dd][h].
__global__ void k_prep(const float* __restrict__ conv_w, const float* __restrict__ fc_w2_w,
                       float* __restrict__ Wt, float* __restrict__ fc2t) {
    int idx = blockIdx.x * 256 + threadIdx.x;
    if (idx < 30000) {
        int kk = idx / 100, h = idx - kk * 100;
        Wt[idx] = conv_w[h * 300 + kk];
    } else if (idx < 40000) {
        int j = idx - 30000;
        int h = j / 100, dd = j - h * 100;
        fc2t[j] = fc_w2_w[dd * 100 + h];
    }
}

// ---------------------------------------------------------------------------
// K1: per (branch, b, r) instance. Block = 128 threads (2 waves), 125 active,
// register tile 10 s' x 4 h. kk-accumulation order identical to the verified
// round-2 kernel (ascending kk, jj 0..3) -> bit-stable z outputs.
__global__ __launch_bounds__(128, 2)
void k_branch(const int* __restrict__ u_rev, const int* __restrict__ i_rev,
              const float* __restrict__ emb, const float* __restrict__ Wt,
              const float* __restrict__ conv_b, const float* __restrict__ fc_w_w,
              const float* __restrict__ fc_w_b, const float* __restrict__ fc_w2_b,
              const float* __restrict__ fc2t, const float* __restrict__ h_r_w,
              const float* __restrict__ h_c_w,
              float* __restrict__ Pbuf, float* __restrict__ zdot,
              float* __restrict__ Pdot, float* __restrict__ z_out) {
    __shared__ __align__(16) char smem[38016];
    float* s_x   = (float*)smem;                 // [5200] embflat fp32; overlaid by s_c[50][104]
    float* s_c   = (float*)smem;
    float* s_w   = (float*)(smem + 20800);       // [40][100] W chunk
    int*   s_tok = (int*)(smem + 36800);         // [52]
    float* s_z   = (float*)(smem + 37008);       // [50]
    float* s_max = (float*)(smem + 37216);       // [100]
    float* s_P   = (float*)(smem + 37616);       // [100]

    const int bid = blockIdx.x;
    const int branch = bid >> 11, inst = bid & 2047;
    const int tid = threadIdx.x, lane = tid & 63, wave = tid >> 6;
    const int* rev = branch ? i_rev : u_rev;

    if (tid < 52) s_tok[tid] = rev[inst * 52 + tid];
    __syncthreads();

    // embedding gather, float4: 52 rows x 25 float4
    {
        const float4* emb4 = (const float4*)emb;
        float4* sx4 = (float4*)s_x;
        for (int idx = tid; idx < 1300; idx += 128) {
            int s = idx / 25, w = idx - s * 25;
            sx4[idx] = emb4[s_tok[s] * 25 + w];
        }
    }

    const bool active = tid < 125;
    const int sg = tid / 25, hg = tid % 25;
    const int s5 = sg * 10, h4 = hg * 4;
    float acc[10][4];
#pragma unroll
    for (int i = 0; i < 10; i++)
#pragma unroll
        for (int t = 0; t < 4; t++) acc[i][t] = 0.f;

    for (int ck = 0; ck < 8; ck++) {
        const int r0 = ck * 40;
        const int nr = (ck < 7) ? 40 : 20;
        __syncthreads();                          // prior chunk reads done (+ gather, ck=0)
        {   // stage W chunk rows r0..r0+nr-1 (nr*25 float4)
            const float4* src = (const float4*)(Wt + r0 * 100);
            float4* dst = (float4*)s_w;
            for (int idx = tid; idx < nr * 25; idx += 128) dst[idx] = src[idx];
        }
        __syncthreads();
        if (active) {
            for (int j = 0; j < nr; j += 4) {
                float4 wb[4];
#pragma unroll
                for (int jj = 0; jj < 4; jj++)
                    wb[jj] = *(const float4*)&s_w[(j + jj) * 100 + h4];
#pragma unroll
                for (int i = 0; i < 10; i++) {
                    float4 xa = *(const float4*)&s_x[(s5 + i) * 100 + r0 + j];
                    const float* xs = (const float*)&xa;
#pragma unroll
                    for (int jj = 0; jj < 4; jj++) {
                        float x = xs[jj];
                        acc[i][0] += x * wb[jj].x;
                        acc[i][1] += x * wb[jj].y;
                        acc[i][2] += x * wb[jj].z;
                        acc[i][3] += x * wb[jj].w;
                    }
                }
            }
        }
    }
    __syncthreads();                              // all s_x/s_w reads done; reuse as s_c

    // c = relu(conv + bias) into s_c[50][104]
    if (active) {
        float cb[4];
#pragma unroll
        for (int t = 0; t < 4; t++) cb[t] = conv_b[h4 + t];
#pragma unroll
        for (int i = 0; i < 10; i++) {
            int sp = s5 + i;
#pragma unroll
            for (int t = 0; t < 4; t++) {
                float v = acc[i][t] + cb[t];
                s_c[sp * 104 + h4 + t] = v > 0.f ? v : 0.f;
            }
        }
    }
    __syncthreads();

    // z per position: 2 threads/position (h-halves), straight-through round
    if (tid < 100) {
        int pos = tid >> 1, q = tid & 1;
        float part = 0.f;
        for (int h = 0; h < 50; h++) part += s_c[pos * 104 + q * 50 + h] * fc_w_w[q * 50 + h];
        part += __shfl_xor(part, 1, 64);
        if (q == 0) {
            float z = rintf(sigmoidf_(part + fc_w_b[0]));
            s_z[pos] = z;
            z_out[branch * 102400 + inst * 50 + pos] = z;
        }
    }
    __syncthreads();

    // column max over positions (c >= 0 post-relu)
    if (tid < 100) {
        float m = 0.f;
        for (int pr = 0; pr < 50; pr++) m = fmaxf(m, s_c[pr * 104 + tid]);
        s_max[tid] = m;
    }
    __syncthreads();

    // P[dd] via transposed fc2t (coalesced): P = fc_w2_b + cmax . fc2t[:,dd]
    if (tid < 100) {
        float a = fc_w2_b[tid];
        for (int h = 0; h < 100; h++) a += s_max[h] * fc2t[h * 100 + tid];
        Pbuf[(branch * 2048 + inst) * 100 + tid] = a;
        s_P[tid] = a;
    }
    __syncthreads();

    // zdot = z . h_r_w[branch half], Pdot = P . h_c_w[branch half]
    if (wave == 0) {
        float v = (lane < 50) ? s_z[lane] * h_r_w[branch * 50 + lane] : 0.f;
        for (int s = 1; s < 64; s <<= 1) v += __shfl_xor(v, s, 64);
        if (lane == 0) zdot[branch * 2048 + inst] = v;
    } else {
        float v = 0.f;
        if (lane < 50) v = s_P[lane] * h_c_w[branch * 100 + lane]
                         + s_P[lane + 50] * h_c_w[branch * 100 + lane + 50];
        for (int s = 1; s < 64; s <<= 1) v += __shfl_xor(v, s, 64);
        if (lane == 0) Pdot[branch * 2048 + inst] = v;
    }
}

// ---------------------------------------------------------------------------
// K2: Psum[br][b][d] = sum_r Pbuf[br][b*8+r][d]  (float4: 12800 elements)
__global__ void k_psum(const float* __restrict__ Pbuf, float* __restrict__ Psum) {
    int idx = blockIdx.x * 256 + threadIdx.x;
    if (idx >= 12800) return;
    int br = idx / 6400, rem = idx - br * 6400;
    int b = rem / 25, w = rem - b * 25;
    const float4* P4 = (const float4*)Pbuf;
    float4 s = make_float4(0.f, 0.f, 0.f, 0.f);
    for (int r = 0; r < 8; r++) {
        float4 v = P4[(br * 2048 + b * 8 + r) * 25 + w];
        s.x += v.x; s.y += v.y; s.z += v.z; s.w += v.w;
    }
    ((float4*)Psum)[idx] = s;
}

// ---------------------------------------------------------------------------
// K3: per-edge, float4-coalesced dot products. One wave per edge,
// 16 groups (8 user rows + 8 item rows) x 4 lanes each.
__launch_bounds__(256)
__global__ void k_edge(const int* __restrict__ uid, const int* __restrict__ iid,
                       const float* __restrict__ Pbuf, const float* __restrict__ Psum,
                       const float* __restrict__ zdot, const float* __restrict__ Pdot,
                       const float* __restrict__ user_bias, const float* __restrict__ item_bias,
                       const float* __restrict__ global_bias, float* __restrict__ out) {
    int wave = threadIdx.x >> 6, lane = threadIdx.x & 63;
    int e = blockIdx.x * 4 + wave;
    int u = uid[e], i = iid[e];
    int g = lane >> 2, q = lane & 3;
    const float4* prow4; const float4* psum4; float wr, wc;
    if (g < 8) {
        prow4 = (const float4*)(Pbuf + (u * 8 + g) * 100);
        psum4 = (const float4*)(Psum + 25600 + i * 100);
        wr = zdot[u * 8 + g]; wc = Pdot[u * 8 + g];
    } else {
        prow4 = (const float4*)(Pbuf + (2048 + i * 8 + (g - 8)) * 100);
        psum4 = (const float4*)(Psum + u * 100);
        wr = zdot[2048 + i * 8 + (g - 8)]; wc = Pdot[2048 + i * 8 + (g - 8)];
    }
    float part = 0.f;
#pragma unroll
    for (int t = 0; t < 7; t++) {
        int w = q + 4 * t;
        if (w < 25) {
            float4 a = prow4[w], b = psum4[w];
            part += a.x * b.x + a.y * b.y + a.z * b.z + a.w * b.w;
        }
    }
    part += __shfl_xor(part, 1, 64);
    part += __shfl_xor(part, 2, 64);
    float sg = sigmoidf_(part);
    float cr = (q == 0) ? sg * wr : 0.f;
    float cc = (q == 0) ? sg * wc : 0.f;
    for (int s = 4; s < 64; s <<= 1) { cr += __shfl_xor(cr, s, 64); cc += __shfl_xor(cc, s, 64); }
    if (lane == 0) {
        out[e] = cr + user_bias[u] + item_bias[i] + global_bias[0];
        out[20000 + e] = cc;
    }
}

// ---------------------------------------------------------------------------
extern "C" void kernel_launch(void* const* d_in, const int* in_sizes, int n_in,
                              void* d_out, int out_size, void* d_ws, size_t ws_size,
                              hipStream_t stream) {
    const int*   u_rev    = (const int*)d_in[0];
    const int*   i_rev    = (const int*)d_in[1];
    const int*   uid      = (const int*)d_in[2];
    const int*   iid      = (const int*)d_in[3];
    const float* emb      = (const float*)d_in[4];
    const float* conv_w   = (const float*)d_in[5];
    const float* conv_b   = (const float*)d_in[6];
    const float* fc_w_w   = (const float*)d_in[7];
    const float* fc_w_b   = (const float*)d_in[8];
    const float* fc_w2_w  = (const float*)d_in[9];
    const float* fc_w2_b  = (const float*)d_in[10];
    const float* h_r_w    = (const float*)d_in[11];
    const float* h_c_w    = (const float*)d_in[12];
    const float* user_b   = (const float*)d_in[13];
    const float* item_b   = (const float*)d_in[14];
    const float* global_b = (const float*)d_in[15];
    float* out = (float*)d_out;

    float* Pbuf  = (float*)d_ws;             // [2][2048][100]
    float* Psum  = Pbuf + 409600;            // [2][256][100]
    float* zdotb = Psum + 51200;             // [2][2048]
    float* Pdotb = zdotb + 4096;             // [2][2048]
    float* Wt    = Pdotb + 4096;             // [300][100]
    float* fc2t  = Wt + 30000;               // [100][100]

    hipLaunchKernelGGL(k_prep, dim3(157), dim3(256), 0, stream, conv_w, fc_w2_w, Wt, fc2t);
    hipLaunchKernelGGL(k_branch, dim3(4096), dim3(128), 0, stream,
                       u_rev, i_rev, emb, Wt, conv_b, fc_w_w, fc_w_b,
                       fc_w2_b, fc2t, h_r_w, h_c_w,
                       Pbuf, zdotb, Pdotb, out + 40000);
    hipLaunchKernelGGL(k_psum, dim3(50), dim3(256), 0, stream, Pbuf, Psum);
    hipLaunchKernelGGL(k_edge, dim3(5000), dim3(256), 0, stream,
                       uid, iid, Pbuf, Psum, zdotb, Pdotb,
                       user_b, item_b, global_b, out);
}

// Round 4
// 283.829 us; speedup vs baseline: 1.0695x; 1.0695x over previous
//
#include <hip/hip_runtime.h>
#include <math.h>

// Model: review-based recommender. ALL float tensors fp32.
// Shapes: VOCAB=20000, D=100, H=100, K=3, N_U=N_I=256, R=8, S=52, Sp=50, E=20000.
// Outputs (fp32, flat): pred_r[20000] @0, pred_c[20000] @20000,
//                       z_u[102400] @40000, z_i[102400] @142400.
//
// R4: latency-bound k_branch -> maximize waves/CU. 256-thr blocks, tile 5x4
// (round-2 bit-identical numerics), W chunk 20 rows -> 30KB LDS -> 5 blk/CU.

__device__ __forceinline__ float sigmoidf_(float x) { return 1.f / (1.f + expf(-x)); }

// ---------------------------------------------------------------------------
// K0: prep. Wt[kk=300][h=100] = conv_w[h][kk]; fc2t[h=100][dd=100] = fc_w2_w[dd][h].
__global__ void k_prep(const float* __restrict__ conv_w, const float* __restrict__ fc_w2_w,
                       float* __restrict__ Wt, float* __restrict__ fc2t) {
    int idx = blockIdx.x * 256 + threadIdx.x;
    if (idx < 30000) {
        int kk = idx / 100, h = idx - kk * 100;
        Wt[idx] = conv_w[h * 300 + kk];
    } else if (idx < 40000) {
        int j = idx - 30000;
        int h = j / 100, dd = j - h * 100;
        fc2t[j] = fc_w2_w[dd * 100 + h];
    }
}

// ---------------------------------------------------------------------------
// K1: per (branch, b, r) instance. 256 threads (250 active), tile 5 s' x 4 h.
// kk-accumulation order bit-identical to the verified round-2 kernel.
// LDS 30016 B -> 5 blocks/CU = 20 waves/CU.
__launch_bounds__(256)
__global__ void k_branch(const int* __restrict__ u_rev, const int* __restrict__ i_rev,
                         const float* __restrict__ emb, const float* __restrict__ Wt,
                         const float* __restrict__ conv_b, const float* __restrict__ fc_w_w,
                         const float* __restrict__ fc_w_b, const float* __restrict__ fc_w2_b,
                         const float* __restrict__ fc2t, const float* __restrict__ h_r_w,
                         const float* __restrict__ h_c_w,
                         float* __restrict__ Pbuf, float* __restrict__ zdot,
                         float* __restrict__ Pdot, float* __restrict__ z_out) {
    __shared__ __align__(16) char smem[30016];
    float* s_x   = (float*)smem;                 // [5200] embflat; overlaid by s_c[50][104]
    float* s_c   = (float*)smem;
    float* s_w   = (float*)(smem + 20800);       // [20][100] W chunk
    int*   s_tok = (int*)(smem + 28800);         // [52]
    float* s_z   = (float*)(smem + 29008);       // [50]
    float* s_max = (float*)(smem + 29208);       // [100]
    float* s_P   = (float*)(smem + 29608);       // [100]

    const int bid = blockIdx.x;
    const int branch = bid >> 11, inst = bid & 2047;
    const int tid = threadIdx.x, lane = tid & 63, wave = tid >> 6;
    const int* rev = branch ? i_rev : u_rev;

    if (tid < 52) s_tok[tid] = rev[inst * 52 + tid];
    __syncthreads();

    // embedding gather, float4: 52 rows x 25 float4
    {
        const float4* emb4 = (const float4*)emb;
        float4* sx4 = (float4*)s_x;
        for (int idx = tid; idx < 1300; idx += 256) {
            int s = idx / 25, w = idx - s * 25;
            sx4[idx] = emb4[s_tok[s] * 25 + w];
        }
    }

    const bool active = tid < 250;
    const int hg = tid % 25, sg = tid / 25;      // sg 0..9 for active threads
    const int h4 = hg * 4, s5 = sg * 5;
    float acc[5][4];
#pragma unroll
    for (int i = 0; i < 5; i++)
#pragma unroll
        for (int t = 0; t < 4; t++) acc[i][t] = 0.f;

    for (int ck = 0; ck < 15; ck++) {
        const int r0 = ck * 20;
        __syncthreads();                         // prior chunk reads done (+ gather, ck=0)
        {   // stage W chunk rows r0..r0+19 (500 float4)
            const float4* src = (const float4*)(Wt + r0 * 100);
            float4* dst = (float4*)s_w;
            for (int i = tid; i < 500; i += 256) dst[i] = src[i];
        }
        __syncthreads();
        if (active) {
            for (int j = 0; j < 20; j += 4) {
                float4 xa[5], wb[4];
#pragma unroll
                for (int i = 0; i < 5; i++)
                    xa[i] = *(const float4*)&s_x[(s5 + i) * 100 + r0 + j];
#pragma unroll
                for (int jj = 0; jj < 4; jj++)
                    wb[jj] = *(const float4*)&s_w[(j + jj) * 100 + h4];
#pragma unroll
                for (int i = 0; i < 5; i++) {
                    const float* xs = (const float*)&xa[i];
#pragma unroll
                    for (int jj = 0; jj < 4; jj++) {
                        float x = xs[jj];
                        acc[i][0] += x * wb[jj].x;
                        acc[i][1] += x * wb[jj].y;
                        acc[i][2] += x * wb[jj].z;
                        acc[i][3] += x * wb[jj].w;
                    }
                }
            }
        }
    }
    __syncthreads();                             // all s_x/s_w reads done; reuse as s_c

    // c = relu(conv + bias) into s_c[50][104]
    if (active) {
        float cb[4];
#pragma unroll
        for (int t = 0; t < 4; t++) cb[t] = conv_b[h4 + t];
#pragma unroll
        for (int i = 0; i < 5; i++) {
            int sp = s5 + i;
#pragma unroll
            for (int t = 0; t < 4; t++) {
                float v = acc[i][t] + cb[t];
                s_c[sp * 104 + h4 + t] = v > 0.f ? v : 0.f;
            }
        }
    }
    __syncthreads();

    // z per position: 4 threads/position, straight-through round (bit-identical to r2)
    if (tid < 200) {
        int pp = tid >> 2, q = tid & 3;
        float part = 0.f;
        for (int h = q * 25; h < q * 25 + 25; h++) part += s_c[pp * 104 + h] * fc_w_w[h];
        part += __shfl_xor(part, 1, 64);
        part += __shfl_xor(part, 2, 64);
        if (q == 0) {
            float z = rintf(sigmoidf_(part + fc_w_b[0]));
            s_z[pp] = z;
            z_out[branch * 102400 + inst * 50 + pp] = z;
        }
    }
    __syncthreads();

    // column max over positions (c >= 0 post-relu)
    if (tid < 100) {
        float m = 0.f;
        for (int pr = 0; pr < 50; pr++) m = fmaxf(m, s_c[pr * 104 + tid]);
        s_max[tid] = m;
    }
    __syncthreads();

    // P[dd] via transposed fc2t (coalesced): P = fc_w2_b + cmax . fc2t[:,dd]
    if (tid < 100) {
        float a = fc_w2_b[tid];
        for (int h = 0; h < 100; h++) a += s_max[h] * fc2t[h * 100 + tid];
        Pbuf[(branch * 2048 + inst) * 100 + tid] = a;
        s_P[tid] = a;
    }
    __syncthreads();

    // zdot = z . h_r_w[branch half], Pdot = P . h_c_w[branch half]
    if (wave == 0) {
        float v = (lane < 50) ? s_z[lane] * h_r_w[branch * 50 + lane] : 0.f;
        for (int s = 1; s < 64; s <<= 1) v += __shfl_xor(v, s, 64);
        if (lane == 0) zdot[branch * 2048 + inst] = v;
    } else if (wave == 1) {
        float v = 0.f;
        if (lane < 50) v = s_P[lane] * h_c_w[branch * 100 + lane]
                         + s_P[lane + 50] * h_c_w[branch * 100 + lane + 50];
        for (int s = 1; s < 64; s <<= 1) v += __shfl_xor(v, s, 64);
        if (lane == 0) Pdot[branch * 2048 + inst] = v;
    }
}

// ---------------------------------------------------------------------------
// K2: Psum[br][b][d] = sum_r Pbuf[br][b*8+r][d]  (float4: 12800 elements)
__global__ void k_psum(const float* __restrict__ Pbuf, float* __restrict__ Psum) {
    int idx = blockIdx.x * 256 + threadIdx.x;
    if (idx >= 12800) return;
    int br = idx / 6400, rem = idx - br * 6400;
    int b = rem / 25, w = rem - b * 25;
    const float4* P4 = (const float4*)Pbuf;
    float4 s = make_float4(0.f, 0.f, 0.f, 0.f);
    for (int r = 0; r < 8; r++) {
        float4 v = P4[(br * 2048 + b * 8 + r) * 25 + w];
        s.x += v.x; s.y += v.y; s.z += v.z; s.w += v.w;
    }
    ((float4*)Psum)[idx] = s;
}

// ---------------------------------------------------------------------------
// K3: per-edge, float4-coalesced dot products. One wave per edge,
// 16 groups (8 user rows + 8 item rows) x 4 lanes each.
__launch_bounds__(256)
__global__ void k_edge(const int* __restrict__ uid, const int* __restrict__ iid,
                       const float* __restrict__ Pbuf, const float* __restrict__ Psum,
                       const float* __restrict__ zdot, const float* __restrict__ Pdot,
                       const float* __restrict__ user_bias, const float* __restrict__ item_bias,
                       const float* __restrict__ global_bias, float* __restrict__ out) {
    int wave = threadIdx.x >> 6, lane = threadIdx.x & 63;
    int e = blockIdx.x * 4 + wave;
    int u = uid[e], i = iid[e];
    int g = lane >> 2, q = lane & 3;
    const float4* prow4; const float4* psum4; float wr, wc;
    if (g < 8) {
        prow4 = (const float4*)(Pbuf + (u * 8 + g) * 100);
        psum4 = (const float4*)(Psum + 25600 + i * 100);
        wr = zdot[u * 8 + g]; wc = Pdot[u * 8 + g];
    } else {
        prow4 = (const float4*)(Pbuf + (2048 + i * 8 + (g - 8)) * 100);
        psum4 = (const float4*)(Psum + u * 100);
        wr = zdot[2048 + i * 8 + (g - 8)]; wc = Pdot[2048 + i * 8 + (g - 8)];
    }
    float part = 0.f;
#pragma unroll
    for (int t = 0; t < 7; t++) {
        int w = q + 4 * t;
        if (w < 25) {
            float4 a = prow4[w], b = psum4[w];
            part += a.x * b.x + a.y * b.y + a.z * b.z + a.w * b.w;
        }
    }
    part += __shfl_xor(part, 1, 64);
    part += __shfl_xor(part, 2, 64);
    float sg = sigmoidf_(part);
    float cr = (q == 0) ? sg * wr : 0.f;
    float cc = (q == 0) ? sg * wc : 0.f;
    for (int s = 4; s < 64; s <<= 1) { cr += __shfl_xor(cr, s, 64); cc += __shfl_xor(cc, s, 64); }
    if (lane == 0) {
        out[e] = cr + user_bias[u] + item_bias[i] + global_bias[0];
        out[20000 + e] = cc;
    }
}

// ---------------------------------------------------------------------------
extern "C" void kernel_launch(void* const* d_in, const int* in_sizes, int n_in,
                              void* d_out, int out_size, void* d_ws, size_t ws_size,
                              hipStream_t stream) {
    const int*   u_rev    = (const int*)d_in[0];
    const int*   i_rev    = (const int*)d_in[1];
    const int*   uid      = (const int*)d_in[2];
    const int*   iid      = (const int*)d_in[3];
    const float* emb      = (const float*)d_in[4];
    const float* conv_w   = (const float*)d_in[5];
    const float* conv_b   = (const float*)d_in[6];
    const float* fc_w_w   = (const float*)d_in[7];
    const float* fc_w_b   = (const float*)d_in[8];
    const float* fc_w2_w  = (const float*)d_in[9];
    const float* fc_w2_b  = (const float*)d_in[10];
    const float* h_r_w    = (const float*)d_in[11];
    const float* h_c_w    = (const float*)d_in[12];
    const float* user_b   = (const float*)d_in[13];
    const float* item_b   = (const float*)d_in[14];
    const float* global_b = (const float*)d_in[15];
    float* out = (float*)d_out;

    float* Pbuf  = (float*)d_ws;             // [2][2048][100]
    float* Psum  = Pbuf + 409600;            // [2][256][100]
    float* zdotb = Psum + 51200;             // [2][2048]
    float* Pdotb = zdotb + 4096;             // [2][2048]
    float* Wt    = Pdotb + 4096;             // [300][100]
    float* fc2t  = Wt + 30000;               // [100][100]

    hipLaunchKernelGGL(k_prep, dim3(157), dim3(256), 0, stream, conv_w, fc_w2_w, Wt, fc2t);
    hipLaunchKernelGGL(k_branch, dim3(4096), dim3(256), 0, stream,
                       u_rev, i_rev, emb, Wt, conv_b, fc_w_w, fc_w_b,
                       fc_w2_b, fc2t, h_r_w, h_c_w,
                       Pbuf, zdotb, Pdotb, out + 40000);
    hipLaunchKernelGGL(k_psum, dim3(50), dim3(256), 0, stream, Pbuf, Psum);
    hipLaunchKernelGGL(k_edge, dim3(5000), dim3(256), 0, stream,
                       uid, iid, Pbuf, Psum, zdotb, Pdotb,
                       user_b, item_b, global_b, out);
}

// Round 5
// 283.725 us; speedup vs baseline: 1.0699x; 1.0004x over previous
//
#include <hip/hip_runtime.h>
#include <math.h>

// Model: review-based recommender. ALL float tensors fp32.
// Shapes: VOCAB=20000, D=100, H=100, K=3, N_U=N_I=256, R=8, S=52, Sp=50, E=20000.
// Outputs (fp32, flat): pred_r[20000] @0, pred_c[20000] @20000,
//                       z_u[102400] @40000, z_i[102400] @142400.
//
// R5: k_branch K-loop is barrier/global-latency bound (VALUBusy pinned 63%
// across occupancies). Fix: register-prefetch of next W chunk so the LDS
// refill needs no global wait. Conv FMA order bit-identical to r2/r4.
// k_psum folded into k_branch via atomicAdd (Psum zeroed in k_prep).

__device__ __forceinline__ float sigmoidf_(float x) { return 1.f / (1.f + expf(-x)); }

// ---------------------------------------------------------------------------
// K0: prep. Wt[kk=300][h=100] = conv_w[h][kk]; fc2t[h=100][dd=100] = fc_w2_w[dd][h];
// zero Psum[2*256*100] (ws is poisoned 0xAA before every launch).
__global__ void k_prep(const float* __restrict__ conv_w, const float* __restrict__ fc_w2_w,
                       float* __restrict__ Wt, float* __restrict__ fc2t,
                       float* __restrict__ Psum) {
    int idx = blockIdx.x * 256 + threadIdx.x;
    if (idx < 30000) {
        int kk = idx / 100, h = idx - kk * 100;
        Wt[idx] = conv_w[h * 300 + kk];
    } else if (idx < 40000) {
        int j = idx - 30000;
        int h = j / 100, dd = j - h * 100;
        fc2t[j] = fc_w2_w[dd * 100 + h];
    } else if (idx < 91200) {
        Psum[idx - 40000] = 0.f;
    }
}

// ---------------------------------------------------------------------------
// K1: per (branch, b, r) instance. 256 threads (250 active), tile 5 s' x 4 h.
// W chunks (20 rows, 8KB) register-prefetched one chunk ahead.
__launch_bounds__(256)
__global__ void k_branch(const int* __restrict__ u_rev, const int* __restrict__ i_rev,
                         const float* __restrict__ emb, const float* __restrict__ Wt,
                         const float* __restrict__ conv_b, const float* __restrict__ fc_w_w,
                         const float* __restrict__ fc_w_b, const float* __restrict__ fc_w2_b,
                         const float* __restrict__ fc2t, const float* __restrict__ h_r_w,
                         const float* __restrict__ h_c_w,
                         float* __restrict__ Pbuf, float* __restrict__ Psum,
                         float* __restrict__ zdot, float* __restrict__ Pdot,
                         float* __restrict__ z_out) {
    __shared__ __align__(16) char smem[30016];
    float* s_x   = (float*)smem;                 // [5200] embflat; overlaid by s_c[50][104]
    float* s_c   = (float*)smem;
    float* s_w   = (float*)(smem + 20800);       // [20][100] W chunk
    int*   s_tok = (int*)(smem + 28800);         // [52]
    float* s_z   = (float*)(smem + 29008);       // [50]
    float* s_max = (float*)(smem + 29208);       // [100]
    float* s_P   = (float*)(smem + 29608);       // [100]

    const int bid = blockIdx.x;
    const int branch = bid >> 11, inst = bid & 2047;
    const int tid = threadIdx.x, lane = tid & 63, wave = tid >> 6;
    const int* rev = branch ? i_rev : u_rev;

    if (tid < 52) s_tok[tid] = rev[inst * 52 + tid];
    __syncthreads();

    // embedding gather, float4: 52 rows x 25 float4
    {
        const float4* emb4 = (const float4*)emb;
        float4* sx4 = (float4*)s_x;
        for (int idx = tid; idx < 1300; idx += 256) {
            int s = idx / 25, w = idx - s * 25;
            sx4[idx] = emb4[s_tok[s] * 25 + w];
        }
    }

    const bool active = tid < 250;
    const int hg = tid % 25, sg = tid / 25;      // sg 0..9 for active threads
    const int h4 = hg * 4, s5 = sg * 5;
    float acc[5][4];
#pragma unroll
    for (int i = 0; i < 5; i++)
#pragma unroll
        for (int t = 0; t < 4; t++) acc[i][t] = 0.f;

    // W chunk = 20 rows = 500 float4. Thread covers idx {tid, tid+256}.
    const float4* Wt4 = (const float4*)Wt;
    float4* sw4 = (float4*)s_w;
    const bool pf1v = tid + 256 < 500;
    float4 pf0 = Wt4[tid < 500 ? tid : 0];       // tid<256 always <500
    float4 pf1 = Wt4[pf1v ? tid + 256 : 0];

    for (int ck = 0; ck < 15; ck++) {
        const int r0 = ck * 20;
        __syncthreads();                         // prior chunk reads done (+ gather, ck=0)
        sw4[tid] = pf0;
        if (pf1v) sw4[tid + 256] = pf1;
        if (ck < 14) {                           // prefetch next chunk (no LDS dependence)
            pf0 = Wt4[(ck + 1) * 500 + tid];
            if (pf1v) pf1 = Wt4[(ck + 1) * 500 + tid + 256];
        }
        __syncthreads();                         // s_w ready
        if (active) {
            for (int j = 0; j < 20; j += 4) {
                float4 xa[5], wb[4];
#pragma unroll
                for (int i = 0; i < 5; i++)
                    xa[i] = *(const float4*)&s_x[(s5 + i) * 100 + r0 + j];
#pragma unroll
                for (int jj = 0; jj < 4; jj++)
                    wb[jj] = *(const float4*)&s_w[(j + jj) * 100 + h4];
#pragma unroll
                for (int i = 0; i < 5; i++) {
                    const float* xs = (const float*)&xa[i];
#pragma unroll
                    for (int jj = 0; jj < 4; jj++) {
                        float x = xs[jj];
                        acc[i][0] += x * wb[jj].x;
                        acc[i][1] += x * wb[jj].y;
                        acc[i][2] += x * wb[jj].z;
                        acc[i][3] += x * wb[jj].w;
                    }
                }
            }
        }
    }
    __syncthreads();                             // all s_x/s_w reads done; reuse as s_c

    // c = relu(conv + bias) into s_c[50][104]
    if (active) {
        float cb[4];
#pragma unroll
        for (int t = 0; t < 4; t++) cb[t] = conv_b[h4 + t];
#pragma unroll
        for (int i = 0; i < 5; i++) {
            int sp = s5 + i;
#pragma unroll
            for (int t = 0; t < 4; t++) {
                float v = acc[i][t] + cb[t];
                s_c[sp * 104 + h4 + t] = v > 0.f ? v : 0.f;
            }
        }
    }
    __syncthreads();

    // z per position: 4 threads/position, straight-through round (bit-identical)
    if (tid < 200) {
        int pp = tid >> 2, q = tid & 3;
        float part = 0.f;
        for (int h = q * 25; h < q * 25 + 25; h++) part += s_c[pp * 104 + h] * fc_w_w[h];
        part += __shfl_xor(part, 1, 64);
        part += __shfl_xor(part, 2, 64);
        if (q == 0) {
            float z = rintf(sigmoidf_(part + fc_w_b[0]));
            s_z[pp] = z;
            z_out[branch * 102400 + inst * 50 + pp] = z;
        }
    }
    __syncthreads();

    // column max over positions (c >= 0 post-relu)
    if (tid < 100) {
        float m = 0.f;
        for (int pr = 0; pr < 50; pr++) m = fmaxf(m, s_c[pr * 104 + tid]);
        s_max[tid] = m;
    }
    __syncthreads();

    // P[dd] via transposed fc2t; also accumulate Psum (replaces k_psum)
    if (tid < 100) {
        float a = fc_w2_b[tid];
        for (int h = 0; h < 100; h++) a += s_max[h] * fc2t[h * 100 + tid];
        Pbuf[(branch * 2048 + inst) * 100 + tid] = a;
        s_P[tid] = a;
        atomicAdd(&Psum[(branch * 256 + (inst >> 3)) * 100 + tid], a);
    }
    __syncthreads();

    // zdot = z . h_r_w[branch half], Pdot = P . h_c_w[branch half]
    if (wave == 0) {
        float v = (lane < 50) ? s_z[lane] * h_r_w[branch * 50 + lane] : 0.f;
        for (int s = 1; s < 64; s <<= 1) v += __shfl_xor(v, s, 64);
        if (lane == 0) zdot[branch * 2048 + inst] = v;
    } else if (wave == 1) {
        float v = 0.f;
        if (lane < 50) v = s_P[lane] * h_c_w[branch * 100 + lane]
                         + s_P[lane + 50] * h_c_w[branch * 100 + lane + 50];
        for (int s = 1; s < 64; s <<= 1) v += __shfl_xor(v, s, 64);
        if (lane == 0) Pdot[branch * 2048 + inst] = v;
    }
}

// ---------------------------------------------------------------------------
// K3: per-edge, float4-coalesced dot products. One wave per edge,
// 16 groups (8 user rows + 8 item rows) x 4 lanes each.
__launch_bounds__(256)
__global__ void k_edge(const int* __restrict__ uid, const int* __restrict__ iid,
                       const float* __restrict__ Pbuf, const float* __restrict__ Psum,
                       const float* __restrict__ zdot, const float* __restrict__ Pdot,
                       const float* __restrict__ user_bias, const float* __restrict__ item_bias,
                       const float* __restrict__ global_bias, float* __restrict__ out) {
    int wave = threadIdx.x >> 6, lane = threadIdx.x & 63;
    int e = blockIdx.x * 4 + wave;
    int u = uid[e], i = iid[e];
    int g = lane >> 2, q = lane & 3;
    const float4* prow4; const float4* psum4; float wr, wc;
    if (g < 8) {
        prow4 = (const float4*)(Pbuf + (u * 8 + g) * 100);
        psum4 = (const float4*)(Psum + 25600 + i * 100);
        wr = zdot[u * 8 + g]; wc = Pdot[u * 8 + g];
    } else {
        prow4 = (const float4*)(Pbuf + (2048 + i * 8 + (g - 8)) * 100);
        psum4 = (const float4*)(Psum + u * 100);
        wr = zdot[2048 + i * 8 + (g - 8)]; wc = Pdot[2048 + i * 8 + (g - 8)];
    }
    float part = 0.f;
#pragma unroll
    for (int t = 0; t < 7; t++) {
        int w = q + 4 * t;
        if (w < 25) {
            float4 a = prow4[w], b = psum4[w];
            part += a.x * b.x + a.y * b.y + a.z * b.z + a.w * b.w;
        }
    }
    part += __shfl_xor(part, 1, 64);
    part += __shfl_xor(part, 2, 64);
    float sg = sigmoidf_(part);
    float cr = (q == 0) ? sg * wr : 0.f;
    float cc = (q == 0) ? sg * wc : 0.f;
    for (int s = 4; s < 64; s <<= 1) { cr += __shfl_xor(cr, s, 64); cc += __shfl_xor(cc, s, 64); }
    if (lane == 0) {
        out[e] = cr + user_bias[u] + item_bias[i] + global_bias[0];
        out[20000 + e] = cc;
    }
}

// ---------------------------------------------------------------------------
extern "C" void kernel_launch(void* const* d_in, const int* in_sizes, int n_in,
                              void* d_out, int out_size, void* d_ws, size_t ws_size,
                              hipStream_t stream) {
    const int*   u_rev    = (const int*)d_in[0];
    const int*   i_rev    = (const int*)d_in[1];
    const int*   uid      = (const int*)d_in[2];
    const int*   iid      = (const int*)d_in[3];
    const float* emb      = (const float*)d_in[4];
    const float* conv_w   = (const float*)d_in[5];
    const float* conv_b   = (const float*)d_in[6];
    const float* fc_w_w   = (const float*)d_in[7];
    const float* fc_w_b   = (const float*)d_in[8];
    const float* fc_w2_w  = (const float*)d_in[9];
    const float* fc_w2_b  = (const float*)d_in[10];
    const float* h_r_w    = (const float*)d_in[11];
    const float* h_c_w    = (const float*)d_in[12];
    const float* user_b   = (const float*)d_in[13];
    const float* item_b   = (const float*)d_in[14];
    const float* global_b = (const float*)d_in[15];
    float* out = (float*)d_out;

    float* Pbuf  = (float*)d_ws;             // [2][2048][100]
    float* Psum  = Pbuf + 409600;            // [2][256][100]
    float* zdotb = Psum + 51200;             // [2][2048]
    float* Pdotb = zdotb + 4096;             // [2][2048]
    float* Wt    = Pdotb + 4096;             // [300][100]
    float* fc2t  = Wt + 30000;               // [100][100]

    hipLaunchKernelGGL(k_prep, dim3(357), dim3(256), 0, stream,
                       conv_w, fc_w2_w, Wt, fc2t, Psum);
    hipLaunchKernelGGL(k_branch, dim3(4096), dim3(256), 0, stream,
                       u_rev, i_rev, emb, Wt, conv_b, fc_w_w, fc_w_b,
                       fc_w2_b, fc2t, h_r_w, h_c_w,
                       Pbuf, Psum, zdotb, Pdotb, out + 40000);
    hipLaunchKernelGGL(k_edge, dim3(5000), dim3(256), 0, stream,
                       uid, iid, Pbuf, Psum, zdotb, Pdotb,
                       user_b, item_b, global_b, out);
}